// Round 4
// baseline (177.795 us; speedup 1.0000x reference)
//
#include <hip/hip_runtime.h>

#define NN 50000
#define EE 600000
#define DD 128
#define MAXDEG 64   // degrees are Poisson(12); P(deg>64) ~ 1e-28
#define NSLICE 32   // privatized BN-stat copies
#define RST 136     // LDS tile row stride in halfwords: 272 B = 17*16 (b128-aligned)
#define UNITS (NN / 16)   // 3125 fused 16-row units (exact, no tail)

typedef __attribute__((ext_vector_type(8))) short short8;
typedef __attribute__((ext_vector_type(4))) float f32x4;

static __device__ __forceinline__ unsigned short f2bf(float f) {
    unsigned int u = __float_as_uint(f);
    u += 0x7FFF + ((u >> 16) & 1);   // round-to-nearest-even
    return (unsigned short)(u >> 16);
}
static __device__ __forceinline__ float bflo(unsigned int u) {
    return __uint_as_float(u << 16);
}
static __device__ __forceinline__ float bfhi(unsigned int u) {
    return __uint_as_float(u & 0xFFFF0000u);
}

// ---------------- dispatch 1: adjacency scatter + weight transpose + x->bf16 ----------------

__global__ __launch_bounds__(256) void k_prep(const float* __restrict__ w1,
                                              const float* __restrict__ w2,
                                              const float* __restrict__ x,
                                              const int* __restrict__ ei,
                                              int* __restrict__ cursor,
                                              unsigned short* __restrict__ srcPad,
                                              unsigned short* __restrict__ wt,
                                              unsigned int* __restrict__ xb) {
    int tid = blockIdx.x * 256 + threadIdx.x;
    if (tid < EE) {
        int s = ei[tid];
        int d = ei[EE + tid];
        int pos = atomicAdd(&cursor[d], 1);
        if (pos < MAXDEG) srcPad[(d << 6) + pos] = (unsigned short)s;
    }
    if (tid < 32768) {
        int w = tid >> 14, idx = tid & 16383;
        int k = idx >> 7, n = idx & 127;
        const float* src = w ? w2 : w1;
        wt[w * 16384 + n * 128 + k] = f2bf(src[k * 128 + n]);
    }
    int xi = tid - 32768;
    if (xi >= 0 && xi < NN * DD / 4) {
        float4 v = ((const float4*)x)[xi];
        uint2 p;
        p.x = (unsigned int)f2bf(v.x) | ((unsigned int)f2bf(v.y) << 16);
        p.y = (unsigned int)f2bf(v.z) | ((unsigned int)f2bf(v.w) << 16);
        ((uint2*)xb)[xi] = p;
    }
}

// ---------------- dispatch 2: fused aggregate -> MLP1 -> MLP2 + BN partials ----------------
// Block = one 16-node unit, 8 waves (512 threads). Each wave aggregates only
// 2 nodes (short dependent-gather chain), then owns exactly one 16-col tile
// in each GEMM stage. W fragments for both layers are prefetched per-wave
// BEFORE the gather chain so their L2 latency hides under it.
// Occupancy: 4 blocks/CU (thread-limited) = 32 waves/CU; LDS 4.4KB/block.

__global__ __launch_bounds__(512) void k_fused(const unsigned int* __restrict__ xb,
                                               const int* __restrict__ cursor,
                                               const unsigned short* __restrict__ srcPad,
                                               const unsigned short* __restrict__ wt,
                                               const float* __restrict__ b1,
                                               const float* __restrict__ b2,
                                               unsigned short* __restrict__ h2b,
                                               float* __restrict__ priv) {
    __shared__ __align__(16) unsigned short tile[16 * RST];  // 4352 B
    int w    = threadIdx.x >> 6;          // 0..7
    int lane = threadIdx.x & 63;
    int unit = blockIdx.x;
    int base = unit * 16;
    int m = lane & 15, quad = lane >> 4;

    // ---- W prefetch (both layers, this wave's col-tile): issue first ----
    short8 wf1[4], wf2[4];
    #pragma unroll
    for (int kc = 0; kc < 4; ++kc) {
        wf1[kc] = *(const short8*)&wt[(w * 16 + m) * 128 + kc * 32 + quad * 8];
        wf2[kc] = *(const short8*)&wt[16384 + (w * 16 + m) * 128 + kc * 32 + quad * 8];
    }

    // ---- aggregation: wave w handles rows {2w, 2w+1} ----
    int ct2[2], sv2[2];
    unsigned int self2[2];
    #pragma unroll
    for (int i = 0; i < 2; ++i) {
        int node = base + w * 2 + i;
        ct2[i]   = cursor[node];
        sv2[i]   = srcPad[(node << 6) + lane];
        self2[i] = xb[(node << 6) + lane];
    }
    #pragma unroll
    for (int i = 0; i < 2; ++i) {
        int cnt = ct2[i] > MAXDEG ? MAXDEG : ct2[i];
        int sv = sv2[i];
        float ax = bflo(self2[i]), ay = bfhi(self2[i]);
        int j = 0;
        for (; j + 8 <= cnt; j += 8) {
            int a0 = __shfl(sv, j, 64),     a1 = __shfl(sv, j + 1, 64);
            int a2 = __shfl(sv, j + 2, 64), a3 = __shfl(sv, j + 3, 64);
            int a4 = __shfl(sv, j + 4, 64), a5 = __shfl(sv, j + 5, 64);
            int a6 = __shfl(sv, j + 6, 64), a7 = __shfl(sv, j + 7, 64);
            unsigned int u0 = xb[(a0 << 6) + lane], u1 = xb[(a1 << 6) + lane];
            unsigned int u2 = xb[(a2 << 6) + lane], u3 = xb[(a3 << 6) + lane];
            unsigned int u4 = xb[(a4 << 6) + lane], u5 = xb[(a5 << 6) + lane];
            unsigned int u6 = xb[(a6 << 6) + lane], u7 = xb[(a7 << 6) + lane];
            ax += bflo(u0) + bflo(u1) + bflo(u2) + bflo(u3)
                + bflo(u4) + bflo(u5) + bflo(u6) + bflo(u7);
            ay += bfhi(u0) + bfhi(u1) + bfhi(u2) + bfhi(u3)
                + bfhi(u4) + bfhi(u5) + bfhi(u6) + bfhi(u7);
        }
        for (; j + 4 <= cnt; j += 4) {
            int a0 = __shfl(sv, j, 64),     a1 = __shfl(sv, j + 1, 64);
            int a2 = __shfl(sv, j + 2, 64), a3 = __shfl(sv, j + 3, 64);
            unsigned int u0 = xb[(a0 << 6) + lane], u1 = xb[(a1 << 6) + lane];
            unsigned int u2 = xb[(a2 << 6) + lane], u3 = xb[(a3 << 6) + lane];
            ax += bflo(u0) + bflo(u1) + bflo(u2) + bflo(u3);
            ay += bfhi(u0) + bfhi(u1) + bfhi(u2) + bfhi(u3);
        }
        for (; j < cnt; ++j) {
            int s = __shfl(sv, j, 64);
            unsigned int u = xb[(s << 6) + lane];
            ax += bflo(u);
            ay += bfhi(u);
        }
        ((unsigned int*)(tile + (w * 2 + i) * RST))[lane] =
            (unsigned int)f2bf(ax) | ((unsigned int)f2bf(ay) << 16);
    }
    __syncthreads();                       // h0 tile complete

    // ---- stage B: h1 = relu(h0 @ W1t + b1); wave w owns col-tile w ----
    short8 af[4];
    #pragma unroll
    for (int kc = 0; kc < 4; ++kc)
        af[kc] = *(const short8*)&tile[m * RST + kc * 32 + quad * 8];
    __syncthreads();                       // all af reads done before tile overwrite
    {
        f32x4 acc = (f32x4)0.f;
        #pragma unroll
        for (int kc = 0; kc < 4; ++kc)
            acc = __builtin_amdgcn_mfma_f32_16x16x32_bf16(af[kc], wf1[kc], acc, 0, 0, 0);
        int col = w * 16 + m;
        float bv = b1[col];
        #pragma unroll
        for (int r = 0; r < 4; ++r)
            tile[(quad * 4 + r) * RST + col] = f2bf(fmaxf(acc[r] + bv, 0.f));
    }
    __syncthreads();                       // h1 tile complete

    // ---- stage C: h2 = h1 @ W2t + b2 -> global + privatized BN partials ----
    #pragma unroll
    for (int kc = 0; kc < 4; ++kc)
        af[kc] = *(const short8*)&tile[m * RST + kc * 32 + quad * 8];
    {
        f32x4 acc = (f32x4)0.f;
        #pragma unroll
        for (int kc = 0; kc < 4; ++kc)
            acc = __builtin_amdgcn_mfma_f32_16x16x32_bf16(af[kc], wf2[kc], acc, 0, 0, 0);
        float* myslice = priv + (unit & (NSLICE - 1)) * 2 * DD;
        int col = w * 16 + m;
        float bv = b2[col];
        float s = 0.f, sq = 0.f;
        #pragma unroll
        for (int r = 0; r < 4; ++r) {
            float v = acc[r] + bv;
            h2b[(base + quad * 4 + r) * 128 + col] = f2bf(v);
            s += v;
            sq += v * v;
        }
        s  += __shfl_down(s, 32, 64);  sq += __shfl_down(sq, 32, 64);
        s  += __shfl_down(s, 16, 64);  sq += __shfl_down(sq, 16, 64);
        if (quad == 0) {
            atomicAdd(&myslice[col], s);
            atomicAdd(&myslice[DD + col], sq);
        }
    }
}

// ---------------- dispatch 3: BN finalize + out = x + relu(bn(h2)) ----------------

__global__ __launch_bounds__(256) void k_final(const float* __restrict__ x,
                                               const unsigned int* __restrict__ h2,
                                               float* __restrict__ out,
                                               const float* __restrict__ priv,
                                               const float* __restrict__ gamma,
                                               const float* __restrict__ beta) {
    __shared__ float ssc[DD], ssh[DD];
    int t = threadIdx.x;
    if (t < DD) {
        float s = 0.f, sq = 0.f;
        #pragma unroll
        for (int sl = 0; sl < NSLICE; ++sl) {
            s  += priv[sl * 2 * DD + t];
            sq += priv[sl * 2 * DD + DD + t];
        }
        float mean = s * (1.0f / NN);
        float var = fmaxf(sq * (1.0f / NN) - mean * mean, 0.f);
        float sc = gamma[t] * rsqrtf(var + 1e-5f);
        ssc[t] = sc;
        ssh[t] = beta[t] - mean * sc;
    }
    __syncthreads();
    #pragma unroll
    for (int u = 0; u < 4; ++u) {
        int idx = blockIdx.x * 1024 + u * 256 + t;
        if (idx >= NN * DD / 4) return;
        int c0 = (idx & 31) * 4;
        unsigned int p0 = h2[2 * idx];
        unsigned int p1 = h2[2 * idx + 1];
        float4 xv = ((const float4*)x)[idx];
        float4 o;
        o.x = xv.x + fmaxf(fmaf(bflo(p0), ssc[c0 + 0], ssh[c0 + 0]), 0.f);
        o.y = xv.y + fmaxf(fmaf(bfhi(p0), ssc[c0 + 1], ssh[c0 + 1]), 0.f);
        o.z = xv.z + fmaxf(fmaf(bflo(p1), ssc[c0 + 2], ssh[c0 + 2]), 0.f);
        o.w = xv.w + fmaxf(fmaf(bfhi(p1), ssc[c0 + 3], ssh[c0 + 3]), 0.f);
        ((float4*)out)[idx] = o;
    }
}

extern "C" void kernel_launch(void* const* d_in, const int* in_sizes, int n_in,
                              void* d_out, int out_size, void* d_ws, size_t ws_size,
                              hipStream_t stream) {
    (void)in_sizes; (void)n_in; (void)out_size; (void)ws_size;
    const float* x     = (const float*)d_in[0];
    const int*   ei    = (const int*)d_in[1];
    const float* w1    = (const float*)d_in[2];
    const float* b1    = (const float*)d_in[3];
    const float* w2    = (const float*)d_in[4];
    const float* b2    = (const float*)d_in[5];
    const float* gamma = (const float*)d_in[6];
    const float* beta  = (const float*)d_in[7];
    float* out = (float*)d_out;
    char* wsb  = (char*)d_ws;

    // ws layout (bytes): cursor 0x0 (200000) | priv 0x31000 (32768) |
    // srcPad 0x40000 (6.4MB) | xb 0x680000 (12.8MB) | h2 0x2C00000 (12.8MB) |
    // wt 0x3880000 (64KB)
    int*            cursor = (int*)wsb;
    float*          priv   = (float*)(wsb + 0x31000);
    unsigned short* srcPad = (unsigned short*)(wsb + 0x40000);
    unsigned int*   xb     = (unsigned int*)(wsb + 0x680000);
    unsigned int*   h2w    = (unsigned int*)(wsb + 0x2C00000);
    unsigned short* wt     = (unsigned short*)(wsb + 0x3880000);
    unsigned short* h2b    = (unsigned short*)h2w;

    // zero cursor + priv
    (void)hipMemsetAsync(wsb, 0, 0x39000, stream);

    // 3-dispatch pipeline; kernel boundaries are the only barriers needed
    k_prep <<<(32768 + NN * DD / 4 + 255) / 256, 256, 0, stream>>>(w1, w2, x, ei, cursor, srcPad, wt, xb);
    k_fused<<<UNITS, 512, 0, stream>>>(xb, cursor, srcPad, wt, b1, b2, h2b, priv);
    k_final<<<(NN * DD / 4 + 1023) / 1024, 256, 0, stream>>>(x, h2w, out, priv, gamma, beta);
}

// Round 5
// 173.112 us; speedup vs baseline: 1.0270x; 1.0270x over previous
//
#include <hip/hip_runtime.h>

#define NN 50000
#define EE 600000
#define DD 128
#define MAXDEG 64   // degrees are Poisson(12); P(deg>64) ~ 1e-28
#define NSLICE 32   // privatized BN-stat copies
#define RST 136     // LDS tile row stride in halfwords: 272 B = 17*16 (b128-aligned)
#define UNITS (NN / 16)   // 3125 fused 16-row units (exact, no tail)

typedef __attribute__((ext_vector_type(8))) short short8;
typedef __attribute__((ext_vector_type(4))) float f32x4;

static __device__ __forceinline__ unsigned short f2bf(float f) {
    unsigned int u = __float_as_uint(f);
    u += 0x7FFF + ((u >> 16) & 1);   // round-to-nearest-even
    return (unsigned short)(u >> 16);
}
static __device__ __forceinline__ float bflo(unsigned int u) {
    return __uint_as_float(u << 16);
}
static __device__ __forceinline__ float bfhi(unsigned int u) {
    return __uint_as_float(u & 0xFFFF0000u);
}

// ---------------- dispatch 1: adjacency scatter + weight transpose + x->bf16 ----------------

__global__ __launch_bounds__(256) void k_prep(const float* __restrict__ w1,
                                              const float* __restrict__ w2,
                                              const float* __restrict__ x,
                                              const int* __restrict__ ei,
                                              int* __restrict__ cursor,
                                              unsigned short* __restrict__ srcPad,
                                              unsigned short* __restrict__ wt,
                                              unsigned int* __restrict__ xb) {
    int tid = blockIdx.x * 256 + threadIdx.x;
    if (tid < EE) {
        int s = ei[tid];
        int d = ei[EE + tid];
        int pos = atomicAdd(&cursor[d], 1);
        if (pos < MAXDEG) srcPad[(d << 6) + pos] = (unsigned short)s;
    }
    if (tid < 32768) {
        int w = tid >> 14, idx = tid & 16383;
        int k = idx >> 7, n = idx & 127;
        const float* src = w ? w2 : w1;
        wt[w * 16384 + n * 128 + k] = f2bf(src[k * 128 + n]);
    }
    int xi = tid - 32768;
    if (xi >= 0 && xi < NN * DD / 4) {
        float4 v = ((const float4*)x)[xi];
        uint2 p;
        p.x = (unsigned int)f2bf(v.x) | ((unsigned int)f2bf(v.y) << 16);
        p.y = (unsigned int)f2bf(v.z) | ((unsigned int)f2bf(v.w) << 16);
        ((uint2*)xb)[xi] = p;
    }
}

// ---------------- dispatch 2: fused aggregate -> MLP1 -> MLP2 + BN partials ----------------
// Block = one 16-node unit, 4 waves (R3's best barrier-coupling config).
// Gather restructure: ONE predicated batch of 16 loads per node (addresses are
// all available upfront via shfl; cnt is wave-uniform so predication is a
// uniform exec-mask; masked lanes add +0.0f). One latency stall group per node
// for ~90% of nodes, instead of 3 (batch8/batch4/singles).

__global__ __launch_bounds__(256) void k_fused(const unsigned int* __restrict__ xb,
                                               const int* __restrict__ cursor,
                                               const unsigned short* __restrict__ srcPad,
                                               const unsigned short* __restrict__ wt,
                                               const float* __restrict__ b1,
                                               const float* __restrict__ b2,
                                               unsigned short* __restrict__ h2b,
                                               float* __restrict__ priv) {
    __shared__ __align__(16) unsigned short tile[16 * RST];  // 4352 B
    int w    = threadIdx.x >> 6;          // 0..3
    int lane = threadIdx.x & 63;
    int unit = blockIdx.x;
    int base = unit * 16;
    int m = lane & 15, quad = lane >> 4;

    // ---- aggregation: wave w handles rows [w*4, w*4+4) ----
    int ct4[4], sv4[4];
    unsigned int self4[4];
    #pragma unroll
    for (int i = 0; i < 4; ++i) {
        int node = base + w * 4 + i;
        ct4[i]   = cursor[node];
        sv4[i]   = srcPad[(node << 6) + lane];
        self4[i] = xb[(node << 6) + lane];
    }
    #pragma unroll
    for (int i = 0; i < 4; ++i) {
        int cnt = ct4[i] > MAXDEG ? MAXDEG : ct4[i];
        int sv = sv4[i];
        float ax = bflo(self4[i]), ay = bfhi(self4[i]);
        {   // batch 0..15, predicated: all 16 loads issue before any consume
            unsigned int buf[16];
            #pragma unroll
            for (int j = 0; j < 16; ++j) {
                int a = __shfl(sv, j, 64);
                buf[j] = (j < cnt) ? xb[(a << 6) + lane] : 0u;
            }
            #pragma unroll
            for (int j = 0; j < 16; ++j) { ax += bflo(buf[j]); ay += bfhi(buf[j]); }
        }
        if (cnt > 16) {   // ~10% of nodes; wave-uniform branch
            unsigned int buf[16];
            #pragma unroll
            for (int j = 0; j < 16; ++j) {
                int a = __shfl(sv, 16 + j, 64);
                buf[j] = (16 + j < cnt) ? xb[(a << 6) + lane] : 0u;
            }
            #pragma unroll
            for (int j = 0; j < 16; ++j) { ax += bflo(buf[j]); ay += bfhi(buf[j]); }
            for (int j = 32; j < cnt; ++j) {   // P(deg>32) ~ 3e-7
                int s = __shfl(sv, j, 64);
                unsigned int u = xb[(s << 6) + lane];
                ax += bflo(u);
                ay += bfhi(u);
            }
        }
        ((unsigned int*)(tile + (w * 4 + i) * RST))[lane] =
            (unsigned int)f2bf(ax) | ((unsigned int)f2bf(ay) << 16);
    }
    __syncthreads();                       // h0 tile complete

    // ---- stage B: h1 = relu(h0 @ W1t + b1); wave w owns col-tiles {2w, 2w+1} ----
    short8 af[4];
    #pragma unroll
    for (int kc = 0; kc < 4; ++kc)
        af[kc] = *(const short8*)&tile[m * RST + kc * 32 + quad * 8];
    __syncthreads();                       // all af reads done before tile overwrite
    {
        short8 wf[2][4];
        #pragma unroll
        for (int t = 0; t < 2; ++t)
            #pragma unroll
            for (int kc = 0; kc < 4; ++kc)
                wf[t][kc] = *(const short8*)&wt[((w * 2 + t) * 16 + m) * 128 + kc * 32 + quad * 8];
        f32x4 acc[2];
        acc[0] = (f32x4)0.f; acc[1] = (f32x4)0.f;
        #pragma unroll
        for (int kc = 0; kc < 4; ++kc)
            #pragma unroll
            for (int t = 0; t < 2; ++t)
                acc[t] = __builtin_amdgcn_mfma_f32_16x16x32_bf16(af[kc], wf[t][kc], acc[t], 0, 0, 0);
        #pragma unroll
        for (int t = 0; t < 2; ++t) {
            int col = (w * 2 + t) * 16 + m;
            float bv = b1[col];
            #pragma unroll
            for (int r = 0; r < 4; ++r)
                tile[(quad * 4 + r) * RST + col] = f2bf(fmaxf(acc[t][r] + bv, 0.f));
        }
    }
    __syncthreads();                       // h1 tile complete

    // ---- stage C: h2 = h1 @ W2t + b2 -> global + privatized BN partials ----
    #pragma unroll
    for (int kc = 0; kc < 4; ++kc)
        af[kc] = *(const short8*)&tile[m * RST + kc * 32 + quad * 8];
    {
        const unsigned short* W2t = wt + 16384;
        short8 wf[2][4];
        #pragma unroll
        for (int t = 0; t < 2; ++t)
            #pragma unroll
            for (int kc = 0; kc < 4; ++kc)
                wf[t][kc] = *(const short8*)&W2t[((w * 2 + t) * 16 + m) * 128 + kc * 32 + quad * 8];
        f32x4 acc[2];
        acc[0] = (f32x4)0.f; acc[1] = (f32x4)0.f;
        #pragma unroll
        for (int kc = 0; kc < 4; ++kc)
            #pragma unroll
            for (int t = 0; t < 2; ++t)
                acc[t] = __builtin_amdgcn_mfma_f32_16x16x32_bf16(af[kc], wf[t][kc], acc[t], 0, 0, 0);
        float* myslice = priv + (unit & (NSLICE - 1)) * 2 * DD;
        #pragma unroll
        for (int t = 0; t < 2; ++t) {
            int col = (w * 2 + t) * 16 + m;
            float bv = b2[col];
            float s = 0.f, sq = 0.f;
            #pragma unroll
            for (int r = 0; r < 4; ++r) {
                float v = acc[t][r] + bv;
                h2b[(base + quad * 4 + r) * 128 + col] = f2bf(v);
                s += v;
                sq += v * v;
            }
            s  += __shfl_down(s, 32, 64);  sq += __shfl_down(sq, 32, 64);
            s  += __shfl_down(s, 16, 64);  sq += __shfl_down(sq, 16, 64);
            if (quad == 0) {
                atomicAdd(&myslice[col], s);
                atomicAdd(&myslice[DD + col], sq);
            }
        }
    }
}

// ---------------- dispatch 3: BN finalize + out = x + relu(bn(h2)) ----------------

__global__ __launch_bounds__(256) void k_final(const float* __restrict__ x,
                                               const unsigned int* __restrict__ h2,
                                               float* __restrict__ out,
                                               const float* __restrict__ priv,
                                               const float* __restrict__ gamma,
                                               const float* __restrict__ beta) {
    __shared__ float ssc[DD], ssh[DD];
    int t = threadIdx.x;
    if (t < DD) {
        float s = 0.f, sq = 0.f;
        #pragma unroll
        for (int sl = 0; sl < NSLICE; ++sl) {
            s  += priv[sl * 2 * DD + t];
            sq += priv[sl * 2 * DD + DD + t];
        }
        float mean = s * (1.0f / NN);
        float var = fmaxf(sq * (1.0f / NN) - mean * mean, 0.f);
        float sc = gamma[t] * rsqrtf(var + 1e-5f);
        ssc[t] = sc;
        ssh[t] = beta[t] - mean * sc;
    }
    __syncthreads();
    #pragma unroll
    for (int u = 0; u < 4; ++u) {
        int idx = blockIdx.x * 1024 + u * 256 + t;
        if (idx >= NN * DD / 4) return;
        int c0 = (idx & 31) * 4;
        unsigned int p0 = h2[2 * idx];
        unsigned int p1 = h2[2 * idx + 1];
        float4 xv = ((const float4*)x)[idx];
        float4 o;
        o.x = xv.x + fmaxf(fmaf(bflo(p0), ssc[c0 + 0], ssh[c0 + 0]), 0.f);
        o.y = xv.y + fmaxf(fmaf(bfhi(p0), ssc[c0 + 1], ssh[c0 + 1]), 0.f);
        o.z = xv.z + fmaxf(fmaf(bflo(p1), ssc[c0 + 2], ssh[c0 + 2]), 0.f);
        o.w = xv.w + fmaxf(fmaf(bfhi(p1), ssc[c0 + 3], ssh[c0 + 3]), 0.f);
        ((float4*)out)[idx] = o;
    }
}

extern "C" void kernel_launch(void* const* d_in, const int* in_sizes, int n_in,
                              void* d_out, int out_size, void* d_ws, size_t ws_size,
                              hipStream_t stream) {
    (void)in_sizes; (void)n_in; (void)out_size; (void)ws_size;
    const float* x     = (const float*)d_in[0];
    const int*   ei    = (const int*)d_in[1];
    const float* w1    = (const float*)d_in[2];
    const float* b1    = (const float*)d_in[3];
    const float* w2    = (const float*)d_in[4];
    const float* b2    = (const float*)d_in[5];
    const float* gamma = (const float*)d_in[6];
    const float* beta  = (const float*)d_in[7];
    float* out = (float*)d_out;
    char* wsb  = (char*)d_ws;

    // ws layout (bytes): cursor 0x0 (200000) | priv 0x31000 (32768) |
    // srcPad 0x40000 (6.4MB) | xb 0x680000 (12.8MB) | h2 0x2C00000 (12.8MB) |
    // wt 0x3880000 (64KB)
    int*            cursor = (int*)wsb;
    float*          priv   = (float*)(wsb + 0x31000);
    unsigned short* srcPad = (unsigned short*)(wsb + 0x40000);
    unsigned int*   xb     = (unsigned int*)(wsb + 0x680000);
    unsigned int*   h2w    = (unsigned int*)(wsb + 0x2C00000);
    unsigned short* wt     = (unsigned short*)(wsb + 0x3880000);
    unsigned short* h2b    = (unsigned short*)h2w;

    // zero cursor + priv
    (void)hipMemsetAsync(wsb, 0, 0x39000, stream);

    // 3-dispatch pipeline; kernel boundaries are the only barriers needed
    k_prep <<<(32768 + NN * DD / 4 + 255) / 256, 256, 0, stream>>>(w1, w2, x, ei, cursor, srcPad, wt, xb);
    k_fused<<<UNITS, 256, 0, stream>>>(xb, cursor, srcPad, wt, b1, b2, h2b, priv);
    k_final<<<(NN * DD / 4 + 1023) / 1024, 256, 0, stream>>>(x, h2w, out, priv, gamma, beta);
}